// Round 25
// baseline (57.392 us; speedup 1.0000x reference)
//
#include <hip/hip_runtime.h>

#define KS    13
#define HALF  6
#define TY    128             // gradient endpoint: halo amp 1.09, 256 blocks = 1/CU
#define NITER (TY + 12)       // 140 staged rows
#define NK    (NITER / 2)     // 70 iterations (= 10*7: template cycle exact)
#define IMG_H 1024
#define IMG_W 1024

__device__ __forceinline__ int reflect_idx(int i, int n) {
    if (i < 0) i = -i;
    if (i >= n) i = 2 * n - 2 - i;
    return i;
}

struct Ctx {
    const float* xin;
    float*       o;
    float        g[KS];
    int          t;        // thread's column granule: cols 4t..4t+3
    int          r0;       // strip's first output row
    bool         interior; // 2 <= t <= 253 : LDS window read needs no column reflect
};

// H-filter one staged row from LDS: 20-float window -> 4 outputs.
__device__ __forceinline__ float4 h_filter(const float* srow, const Ctx& cx) {
    float f[20];
    if (cx.interior) {
        #pragma unroll
        for (int k = 0; k < 5; ++k) {
            float4 v = *reinterpret_cast<const float4*>(srow + 4 * cx.t - 8 + 4 * k);
            f[4*k+0] = v.x; f[4*k+1] = v.y; f[4*k+2] = v.z; f[4*k+3] = v.w;
        }
    } else {
        #pragma unroll
        for (int k = 0; k < 20; ++k)
            f[k] = srow[reflect_idx(4 * cx.t - 8 + k, IMG_W)];
    }
    float4 h = make_float4(0.f, 0.f, 0.f, 0.f);
    #pragma unroll
    for (int j = 0; j < KS; ++j) {
        h.x += cx.g[j] * f[2 + j];
        h.y += cx.g[j] * f[3 + j];
        h.z += cx.g[j] * f[4 + j];
        h.w += cx.g[j] * f[5 + j];
    }
    return h;
}

// Iteration k (= outer*7 + U, U == k mod 7): stage rows 2k,2k+1 -> (k&1) LDS
// pair; prefetch rows 2k+2,2k+3 (T14); barrier; V[k-1] (lagged, pure register
// math overlapping H's ds_reads) -> output rows r0+2k-14, r0+2k-13; then H[k]
// into slots (2U)%14,(2U+1)%14 (row m lives at slot m%14; 2k%14 == 2U).
// Window indices compile-time (rule #20); ping-pong WAR proof as R13.
template<int U>
__device__ __forceinline__ void body2(int outer, const Ctx& cx, float (*s)[IMG_W],
                                      float4 (&w)[14], float4& cur0, float4& cur1)
{
    const int k = outer * 7 + U;
    if (k >= NK) return;                 // block-uniform guard (barrier-safe)
    const int n0 = 2 * k;
    const int bp = (k & 1) * 2;          // LDS buffer pair

    // commit staged rows; then issue next pair's loads (T14)
    *reinterpret_cast<float4*>(&s[bp + 0][4 * cx.t]) = cur0;
    *reinterpret_cast<float4*>(&s[bp + 1][4 * cx.t]) = cur1;
    if (k + 1 < NK) {
        const int ra = reflect_idx(cx.r0 + n0 - 4, IMG_H);  // row n0+2
        const int rb = reflect_idx(cx.r0 + n0 - 3, IMG_H);  // row n0+3
        cur0 = *reinterpret_cast<const float4*>(cx.xin + (size_t)ra * IMG_W + 4 * cx.t);
        cur1 = *reinterpret_cast<const float4*>(cx.xin + (size_t)rb * IMG_W + 4 * cx.t);
    }
    __syncthreads();

    // V[k-1] (lagged): output rows r0+n0-14, r0+n0-13; taps slots (2U+j)%14,
    // (2U+1+j)%14 -- all pre-H window values.
    if (n0 >= 14) {
        float4 a0 = make_float4(0.f, 0.f, 0.f, 0.f);
        float4 a1 = make_float4(0.f, 0.f, 0.f, 0.f);
        #pragma unroll
        for (int j = 0; j < KS; ++j) {
            const float4 v0 = w[(2 * U + j) % 14];
            const float4 v1 = w[(2 * U + 1 + j) % 14];
            a0.x += cx.g[j] * v0.x;  a1.x += cx.g[j] * v1.x;
            a0.y += cx.g[j] * v0.y;  a1.y += cx.g[j] * v1.y;
            a0.z += cx.g[j] * v0.z;  a1.z += cx.g[j] * v1.z;
            a0.w += cx.g[j] * v0.w;  a1.w += cx.g[j] * v1.w;
        }
        *reinterpret_cast<float4*>(cx.o + (size_t)(cx.r0 + n0 - 14) * IMG_W + 4 * cx.t) = a0;
        *reinterpret_cast<float4*>(cx.o + (size_t)(cx.r0 + n0 - 13) * IMG_W + 4 * cx.t) = a1;
    }

    // H[k]: ds_reads are independent of the V math above -> scheduler overlaps
    w[(2 * U) % 14]     = h_filter(s[bp + 0], cx);
    w[(2 * U + 1) % 14] = h_filter(s[bp + 1], cx);
}

// No launch-bounds min-waves (R2: VGPR cap -> spill). Expect ~96 VGPR.
__global__ __launch_bounds__(256) void gauss_blur_stream(
    const float* __restrict__ x, const float* __restrict__ k2d,
    float* __restrict__ out)
{
    __shared__ float s[4][IMG_W];   // 16384 B: two ping-pong row PAIRS

    Ctx cx;
    cx.t  = threadIdx.x;
    cx.r0 = blockIdx.x * TY;
    const int img = blockIdx.y;
    cx.xin = x + (size_t)img * IMG_H * IMG_W;
    cx.o   = out + (size_t)img * IMG_H * IMG_W;
    cx.interior = (cx.t >= 2) && (cx.t <= 253);

    // 1D taps: k2d = outer(g,g) exactly, g[i] = k2d[i][6]/sqrt(k2d[6][6])
    {
        float c   = k2d[HALF * KS + HALF];
        float inv = 1.0f / sqrtf(c);
        #pragma unroll
        for (int j = 0; j < KS; ++j) cx.g[j] = k2d[j * KS + HALF] * inv;
    }

    float4 w[14];
    // preload rows n=0,1 (input rows r0-6, r0-5, reflected)
    float4 cur0 = *reinterpret_cast<const float4*>(
        cx.xin + (size_t)reflect_idx(cx.r0 - 6, IMG_H) * IMG_W + 4 * cx.t);
    float4 cur1 = *reinterpret_cast<const float4*>(
        cx.xin + (size_t)reflect_idx(cx.r0 - 5, IMG_H) * IMG_W + 4 * cx.t);

    for (int outer = 0; outer < 10; ++outer) {   // 10*7 = 70 bodies = NK exactly
        body2<0>(outer, cx, s, w, cur0, cur1);
        body2<1>(outer, cx, s, w, cur0, cur1);
        body2<2>(outer, cx, s, w, cur0, cur1);
        body2<3>(outer, cx, s, w, cur0, cur1);
        body2<4>(outer, cx, s, w, cur0, cur1);
        body2<5>(outer, cx, s, w, cur0, cur1);
        body2<6>(outer, cx, s, w, cur0, cur1);
    }

    // epilogue: V[69] -> output rows r0+126, r0+127. As-if k'=70 (70 mod 7 = 0):
    // taps slots (j)%14, (1+j)%14 (row 126 = 9*14 -> slot 0).
    {
        float4 a0 = make_float4(0.f, 0.f, 0.f, 0.f);
        float4 a1 = make_float4(0.f, 0.f, 0.f, 0.f);
        #pragma unroll
        for (int j = 0; j < KS; ++j) {
            const float4 v0 = w[(j) % 14];
            const float4 v1 = w[(1 + j) % 14];
            a0.x += cx.g[j] * v0.x;  a1.x += cx.g[j] * v1.x;
            a0.y += cx.g[j] * v0.y;  a1.y += cx.g[j] * v1.y;
            a0.z += cx.g[j] * v0.z;  a1.z += cx.g[j] * v1.z;
            a0.w += cx.g[j] * v0.w;  a1.w += cx.g[j] * v1.w;
        }
        *reinterpret_cast<float4*>(cx.o + (size_t)(cx.r0 + 126) * IMG_W + 4 * cx.t) = a0;
        *reinterpret_cast<float4*>(cx.o + (size_t)(cx.r0 + 127) * IMG_W + 4 * cx.t) = a1;
    }
}

extern "C" void kernel_launch(void* const* d_in, const int* in_sizes, int n_in,
                              void* d_out, int out_size, void* d_ws, size_t ws_size,
                              hipStream_t stream) {
    const float* x   = (const float*)d_in[0];
    const float* k2d = (const float*)d_in[1];
    float*       out = (float*)d_out;

    dim3 grid(IMG_H / TY, 32);   // 8 strips x 32 images = 256 blocks (1/CU)
    gauss_blur_stream<<<grid, 256, 0, stream>>>(x, k2d, out);
}

// Round 26
// 51.271 us; speedup vs baseline: 1.1194x; 1.1194x over previous
//
#include <hip/hip_runtime.h>

#define KS    13
#define HALF  6
#define TY    64              // amplification/stream optimum (R24: 32->54.0, 64->51.9, 128->57.4)
#define NITER (TY + 12)       // 76 staged rows
#define NK    (NITER / 2)     // 38 iterations, 2 rows per barrier
#define IMG_H 1024
#define IMG_W 1024

typedef float vfloat4 __attribute__((ext_vector_type(4)));  // native vec for nt-store

__device__ __forceinline__ int reflect_idx(int i, int n) {
    if (i < 0) i = -i;
    if (i >= n) i = 2 * n - 2 - i;
    return i;
}

struct Ctx {
    const float* xin;
    float*       o;
    float        g[KS];
    int          t;        // thread's column granule: cols 4t..4t+3
    int          r0;       // strip's first output row
    bool         interior; // 2 <= t <= 253 : LDS window read needs no column reflect
};

// Nontemporal float4 store: output is write-once/never-read -- bypassing normal
// cache retention keeps the L3-resident INPUT from being evicted by the write
// stream (FETCH was 77 MB vs 153 MB logical reads: L3 held ~half; writes evict).
__device__ __forceinline__ void nt_store4(float* p, const float4& a) {
    vfloat4 v = { a.x, a.y, a.z, a.w };
    __builtin_nontemporal_store(v, reinterpret_cast<vfloat4*>(p));
}

// H-filter one staged row from LDS: 20-float window -> 4 outputs.
__device__ __forceinline__ float4 h_filter(const float* srow, const Ctx& cx) {
    float f[20];
    if (cx.interior) {
        #pragma unroll
        for (int k = 0; k < 5; ++k) {
            float4 v = *reinterpret_cast<const float4*>(srow + 4 * cx.t - 8 + 4 * k);
            f[4*k+0] = v.x; f[4*k+1] = v.y; f[4*k+2] = v.z; f[4*k+3] = v.w;
        }
    } else {
        #pragma unroll
        for (int k = 0; k < 20; ++k)
            f[k] = srow[reflect_idx(4 * cx.t - 8 + k, IMG_W)];
    }
    float4 h = make_float4(0.f, 0.f, 0.f, 0.f);
    #pragma unroll
    for (int j = 0; j < KS; ++j) {
        h.x += cx.g[j] * f[2 + j];
        h.y += cx.g[j] * f[3 + j];
        h.z += cx.g[j] * f[4 + j];
        h.w += cx.g[j] * f[5 + j];
    }
    return h;
}

// Iteration k (= outer*7 + U, U == k mod 7): stage rows 2k,2k+1 -> (k&1) LDS
// pair; prefetch rows 2k+2,2k+3 (T14); barrier; V[k-1] (lagged, pure register
// math overlapping H's ds_reads) -> output rows r0+2k-14, r0+2k-13; then H[k]
// into slots (2U)%14,(2U+1)%14 (row m lives at slot m%14; 2k%14 == 2U).
// Window indices compile-time (rule #20); ping-pong WAR proof as R13.
template<int U>
__device__ __forceinline__ void body2(int outer, const Ctx& cx, float (*s)[IMG_W],
                                      float4 (&w)[14], float4& cur0, float4& cur1)
{
    const int k = outer * 7 + U;
    if (k >= NK) return;                 // block-uniform guard (barrier-safe)
    const int n0 = 2 * k;
    const int bp = (k & 1) * 2;          // LDS buffer pair

    // commit staged rows; then issue next pair's loads (T14)
    *reinterpret_cast<float4*>(&s[bp + 0][4 * cx.t]) = cur0;
    *reinterpret_cast<float4*>(&s[bp + 1][4 * cx.t]) = cur1;
    if (k + 1 < NK) {
        const int ra = reflect_idx(cx.r0 + n0 - 4, IMG_H);  // row n0+2
        const int rb = reflect_idx(cx.r0 + n0 - 3, IMG_H);  // row n0+3
        cur0 = *reinterpret_cast<const float4*>(cx.xin + (size_t)ra * IMG_W + 4 * cx.t);
        cur1 = *reinterpret_cast<const float4*>(cx.xin + (size_t)rb * IMG_W + 4 * cx.t);
    }
    __syncthreads();

    // V[k-1] (lagged): output rows r0+n0-14, r0+n0-13; taps slots (2U+j)%14,
    // (2U+1+j)%14 -- all pre-H window values.
    if (n0 >= 14) {
        float4 a0 = make_float4(0.f, 0.f, 0.f, 0.f);
        float4 a1 = make_float4(0.f, 0.f, 0.f, 0.f);
        #pragma unroll
        for (int j = 0; j < KS; ++j) {
            const float4 v0 = w[(2 * U + j) % 14];
            const float4 v1 = w[(2 * U + 1 + j) % 14];
            a0.x += cx.g[j] * v0.x;  a1.x += cx.g[j] * v1.x;
            a0.y += cx.g[j] * v0.y;  a1.y += cx.g[j] * v1.y;
            a0.z += cx.g[j] * v0.z;  a1.z += cx.g[j] * v1.z;
            a0.w += cx.g[j] * v0.w;  a1.w += cx.g[j] * v1.w;
        }
        nt_store4(cx.o + (size_t)(cx.r0 + n0 - 14) * IMG_W + 4 * cx.t, a0);
        nt_store4(cx.o + (size_t)(cx.r0 + n0 - 13) * IMG_W + 4 * cx.t, a1);
    }

    // H[k]: ds_reads are independent of the V math above -> scheduler overlaps
    w[(2 * U) % 14]     = h_filter(s[bp + 0], cx);
    w[(2 * U + 1) % 14] = h_filter(s[bp + 1], cx);
}

// No launch-bounds min-waves (R2: VGPR cap -> spill). Expect ~96 VGPR.
__global__ __launch_bounds__(256) void gauss_blur_stream(
    const float* __restrict__ x, const float* __restrict__ k2d,
    float* __restrict__ out)
{
    __shared__ float s[4][IMG_W];   // 16384 B: two ping-pong row PAIRS

    Ctx cx;
    cx.t  = threadIdx.x;
    cx.r0 = blockIdx.x * TY;
    const int img = blockIdx.y;
    cx.xin = x + (size_t)img * IMG_H * IMG_W;
    cx.o   = out + (size_t)img * IMG_H * IMG_W;
    cx.interior = (cx.t >= 2) && (cx.t <= 253);

    // 1D taps: k2d = outer(g,g) exactly, g[i] = k2d[i][6]/sqrt(k2d[6][6])
    {
        float c   = k2d[HALF * KS + HALF];
        float inv = 1.0f / sqrtf(c);
        #pragma unroll
        for (int j = 0; j < KS; ++j) cx.g[j] = k2d[j * KS + HALF] * inv;
    }

    float4 w[14];
    // preload rows n=0,1 (input rows r0-6, r0-5, reflected)
    float4 cur0 = *reinterpret_cast<const float4*>(
        cx.xin + (size_t)reflect_idx(cx.r0 - 6, IMG_H) * IMG_W + 4 * cx.t);
    float4 cur1 = *reinterpret_cast<const float4*>(
        cx.xin + (size_t)reflect_idx(cx.r0 - 5, IMG_H) * IMG_W + 4 * cx.t);

    for (int outer = 0; outer < 6; ++outer) {   // 6*7 = 42 bodies, guard k<38
        body2<0>(outer, cx, s, w, cur0, cur1);
        body2<1>(outer, cx, s, w, cur0, cur1);
        body2<2>(outer, cx, s, w, cur0, cur1);
        body2<3>(outer, cx, s, w, cur0, cur1);
        body2<4>(outer, cx, s, w, cur0, cur1);
        body2<5>(outer, cx, s, w, cur0, cur1);
        body2<6>(outer, cx, s, w, cur0, cur1);
    }

    // epilogue: V[37] -> output rows r0+62, r0+63. As-if k'=38 (38 mod 7 = 3):
    // taps slots (6+j)%14, (7+j)%14.
    {
        float4 a0 = make_float4(0.f, 0.f, 0.f, 0.f);
        float4 a1 = make_float4(0.f, 0.f, 0.f, 0.f);
        #pragma unroll
        for (int j = 0; j < KS; ++j) {
            const float4 v0 = w[(6 + j) % 14];
            const float4 v1 = w[(7 + j) % 14];
            a0.x += cx.g[j] * v0.x;  a1.x += cx.g[j] * v1.x;
            a0.y += cx.g[j] * v0.y;  a1.y += cx.g[j] * v1.y;
            a0.z += cx.g[j] * v0.z;  a1.z += cx.g[j] * v1.z;
            a0.w += cx.g[j] * v0.w;  a1.w += cx.g[j] * v1.w;
        }
        nt_store4(cx.o + (size_t)(cx.r0 + 62) * IMG_W + 4 * cx.t, a0);
        nt_store4(cx.o + (size_t)(cx.r0 + 63) * IMG_W + 4 * cx.t, a1);
    }
}

extern "C" void kernel_launch(void* const* d_in, const int* in_sizes, int n_in,
                              void* d_out, int out_size, void* d_ws, size_t ws_size,
                              hipStream_t stream) {
    const float* x   = (const float*)d_in[0];
    const float* k2d = (const float*)d_in[1];
    float*       out = (float*)d_out;

    dim3 grid(IMG_H / TY, 32);   // 16 strips x 32 images = 512 blocks
    gauss_blur_stream<<<grid, 256, 0, stream>>>(x, k2d, out);
}